// Round 1
// baseline (4813.900 us; speedup 1.0000x reference)
//
#include <hip/hip_runtime.h>
#include <math.h>

#define BS 256
#define NN 2048
#define KK 64
#define KP1 65
#define NTHREADS 1024
#define NTEAMS 256           // NTHREADS/4 teams; 4 lanes per team
#define ROWS_PT 8            // NN / NTEAMS rows per team
#define MAX_ITER 200
#define SLABR 16             // LDS reduction slab rows

// ---- monotone float<->uint encoding for atomic min/max ----
__device__ __forceinline__ unsigned enc_f32(float f) {
    unsigned b = __float_as_uint(f);
    return b ^ (unsigned)(((int)b >> 31) | (int)0x80000000);
}
__device__ __forceinline__ float dec_f32(unsigned e) {
    unsigned b = (e & 0x80000000u) ? (e & 0x7FFFFFFFu) : ~e;
    return __uint_as_float(b);
}

// ---- kernel 1: global min/max of scores (ignoring -inf for min), count -inf ----
__global__ void minmax_kernel(const float* __restrict__ s,
                              unsigned* __restrict__ maxenc,
                              unsigned* __restrict__ minenc,
                              unsigned* __restrict__ infc) {
    int tid = blockIdx.x * blockDim.x + threadIdx.x;
    int stride = gridDim.x * blockDim.x;
    float mx = -INFINITY, mn = INFINITY;
    unsigned cnt = 0;
    for (int i = tid; i < BS * NN; i += stride) {
        float v = s[i];
        if (isinf(v) && v < 0.0f) cnt++;
        else { mx = fmaxf(mx, v); mn = fminf(mn, v); }
    }
    for (int off = 32; off > 0; off >>= 1) {
        mx = fmaxf(mx, __shfl_down(mx, off));
        mn = fminf(mn, __shfl_down(mn, off));
        cnt += __shfl_down(cnt, off);
    }
    __shared__ float smx[8], smn[8];
    __shared__ unsigned scnt[8];
    int wid = threadIdx.x >> 6, lane = threadIdx.x & 63;
    if (lane == 0) { smx[wid] = mx; smn[wid] = mn; scnt[wid] = cnt; }
    __syncthreads();
    if (threadIdx.x == 0) {
        int nw = blockDim.x >> 6;
        for (int w = 1; w < nw; w++) { mx = fmaxf(mx, smx[w]); mn = fminf(mn, smn[w]); cnt += scnt[w]; }
        atomicMax(maxenc, enc_f32(mx));
        atomicMin(minenc, enc_f32(mn));
        if (cnt) atomicAdd(infc, cnt);
    }
}

// ---- kernel 2: per-batch sort + tau + Gamma0 + 200-iter Sinkhorn + outputs ----
// Factorization: G_ij = exp2(negc2*(s_i-a_j)^2) = p_i * q_j * w_i^(a_j) with
//   w_i = exp2(-2*negc2*s_i), p_i = exp2(negc2*s_i^2), q_j = exp2(negc2*a_j^2).
// Sinkhorn on M_ij = w_i^(64-j) with vt0 = q/65 is exactly equivalent to the
// reference iteration (ut = u*p, vt = q*v for every iterate; Gamma = ut*M*vt).
// Row sums via segmented Horner in w (1 fma/elem, no G materialized);
// col sums via geometric chain (1 mul + 1 fma /elem); col j=64 has M=1.
// Per-row anchors w, wc = w^(49-16*seg) live in VGPRs (no ganc/tanc LDS).
// 1024 threads -> 16 waves/CU (4/SIMD) for latency hiding; VGPR <= 128.
__global__ void __launch_bounds__(NTHREADS)
sink_main(const float* __restrict__ scores, const float* __restrict__ W,
          float* __restrict__ out,
          const unsigned* __restrict__ maxenc, const unsigned* __restrict__ minenc,
          const unsigned* __restrict__ infc, double* __restrict__ norm_acc)
{
    const int tid  = threadIdx.x;
    const int b    = blockIdx.x;
    const int team = tid >> 2;     // 0..255
    const int seg  = tid & 3;      // 0..3
    const int h16  = team & 15;    // slab row (distinct within each wave)

    __shared__ float ss[NN];                                   // filled scores
    __shared__ float srt[NN];                                  // sort buf; later ut per row
    __shared__ float v_sh[68] __attribute__((aligned(16)));    // vt (65 used)
    __shared__ float vprev_sh[68];                             // vt_{t-1}
    __shared__ float slab[2][SLABR * KP1] __attribute__((aligned(16)));
    __shared__ double red_sh[NTHREADS];
    __shared__ float recS_sh[KK];
    __shared__ float topk_sh[KK];

    const float LOG2E   = 1.4426950408889634f;
    const float inv_n   = 1.0f / 2048.0f;        // exact
    const float nu_last = 1984.0f / 2048.0f;     // exact

    // global scalars
    float smax = dec_f32(*maxenc);
    float smin = dec_f32(*minenc);
    unsigned icnt = *infc;
    float filled = smin - (smax - smin);
    float slo = (icnt > 0) ? filled : smin;
    // C.max() attained at an extreme s with anchor 0 or 64 (convexity)
    float cA = slo * slo, cB = (slo - 64.0f) * (slo - 64.0f);
    float cC = smax * smax, cD = (smax - 64.0f) * (smax - 64.0f);
    float Cmax = fmaxf(fmaxf(cA, cB), fmaxf(cC, cD));
    float negc2 = -(10.0f * LOG2E) / Cmax;       // exp(-C/Cmax/0.1) == exp2(d*d*negc2)
    float m2 = -2.0f * negc2;                    // w = exp2(m2 * s)

    // load + -inf fill
    for (int i = tid; i < NN; i += NTHREADS) {
        float v = scores[(size_t)b * NN + i];
        if (isinf(v) && v < 0.0f) v = filled;
        ss[i] = v; srt[i] = v;
    }
    __syncthreads();

    // bitonic sort (ascending); 1 pair per thread per substep
    for (int size = 2; size <= NN; size <<= 1) {
        for (int stride = size >> 1; stride > 0; stride >>= 1) {
            #pragma unroll
            for (int pp = 0; pp < (NN / 2) / NTHREADS; pp++) {
                int p = tid + pp * NTHREADS;
                int lo = ((p & ~(stride - 1)) << 1) | (p & (stride - 1));
                int hi = lo + stride;
                bool up = ((lo & size) == 0);
                float x = srt[lo], y = srt[hi];
                if ((x > y) == up) { srt[lo] = y; srt[hi] = x; }
            }
            __syncthreads();
        }
    }

    // topk (descending) from sorted
    for (int k = tid; k < KK; k += NTHREADS) topk_sh[k] = srt[NN - 1 - k];

    // tau = sum(sorted * W), fp64 accumulate
    double tp = 0.0;
    for (int i = tid; i < NN; i += NTHREADS) tp += (double)srt[i] * (double)W[i];
    red_sh[tid] = tp;
    __syncthreads();
    for (int s2 = NTHREADS / 2; s2 > 0; s2 >>= 1) {
        if (tid < s2) red_sh[tid] += red_sh[tid + s2];
        __syncthreads();
    }
    float tau = (float)red_sh[0];
    float lt = LOG2E / tau;                      // sigma = 1/(1+exp2(|d|*lt))

    // init vt0 = q/65 (q_j = exp2(negc2*(64-j)^2)); zero both slabs
    if (tid < KP1) {
        float a = (float)(KK - tid);
        v_sh[tid] = __builtin_amdgcn_exp2f(negc2 * a * a) * (1.0f / 65.0f);
    }
    for (int q = tid; q < 2 * SLABR * KP1; q += NTHREADS) ((float*)slab)[q] = 0.0f;

    // per-row register anchors: w and wc = w^(49-16*seg)
    float w_[ROWS_PT], wc_[ROWS_PT];
    #pragma unroll
    for (int r = 0; r < ROWS_PT; r++) {
        int row = team + NTEAMS * r;
        float wv = __builtin_amdgcn_exp2f(m2 * ss[row]);
        w_[r] = wv;
        float w2 = wv * wv, w4 = w2 * w2, w8 = w4 * w4, w16 = w8 * w8;
        float wcv = wv;                          // seg3: w^1
        if (seg < 3) wcv *= w16;                 // seg2: w^17
        if (seg < 2) wcv *= w16;                 // seg1: w^33
        if (seg < 1) wcv *= w16;                 // seg0: w^49
        wc_[r] = wcv;
    }
    __syncthreads();

    // ---- Gamma0 column sums S_k into slab[1] (re-zeroed by iter t=0) ----
    {
        float tk[16];
        #pragma unroll
        for (int kk = 0; kk < 16; kk++) tk[kk] = topk_sh[seg * 16 + kk];
        float part[16];
        #pragma unroll
        for (int kk = 0; kk < 16; kk++) part[kk] = 0.0f;
        #pragma unroll 1
        for (int r = 0; r < ROWS_PT; r++) {
            float si = ss[team + NTEAMS * r];
            #pragma unroll
            for (int kk = 0; kk < 16; kk++) {
                float d = fabsf(tk[kk] - si);
                float e = __builtin_amdgcn_exp2f(d * lt);
                part[kk] += 1.0f / (1.0f + e) + 1e-20f;
            }
        }
        #pragma unroll
        for (int kk = 0; kk < 16; kk++)
            atomicAdd(&slab[1][h16 * KP1 + seg * 16 + kk], part[kk]);
    }
    __syncthreads();
    if (tid < KK) {
        float sum = 0.0f;
        #pragma unroll
        for (int g = 0; g < SLABR; g++) sum += slab[1][g * KP1 + tid];
        recS_sh[tid] = 1.0f / sum;
    }
    __syncthreads();

    // ---- Sinkhorn: 200 iterations, Horner row pass + chained col pass ----
    for (int t = 0; t < MAX_ITER; t++) {
        float* sl  = &slab[t & 1][0];
        float* slz = &slab[(t + 1) & 1][0];

        float vloc[16], v64;
        #pragma unroll
        for (int q = 0; q < 4; q++) {
            float4 vv = ((const float4*)(v_sh + seg * 16))[q];
            vloc[4 * q + 0] = vv.x; vloc[4 * q + 1] = vv.y;
            vloc[4 * q + 2] = vv.z; vloc[4 * q + 3] = vv.w;
        }
        v64 = v_sh[64];
        float cp[16];
        #pragma unroll
        for (int j = 0; j < 16; j++) cp[j] = 0.0f;
        float c64 = 0.0f;
        // zero next-iteration slab (readers done before this iter's entry)
        for (int q = tid; q < SLABR * KP1; q += NTHREADS) slz[q] = 0.0f;

        #pragma unroll
        for (int pr = 0; pr < ROWS_PT / 2; pr++) {
            const float wA  = w_[2 * pr],  wB  = w_[2 * pr + 1];
            const float wcA = wc_[2 * pr], wcB = wc_[2 * pr + 1];
            // row sums: Horner in w over this lane's 16 coefficients
            float hA = vloc[0], hB = vloc[0];
            #pragma unroll
            for (int m = 1; m < 16; m++) {
                hA = fmaf(hA, wA, vloc[m]);
                hB = fmaf(hB, wB, vloc[m]);
            }
            float pA = hA * wcA, pB = hB * wcB;
            if (seg == 3) { pA += v64; pB += v64; }   // j=64 term, M=1
            pA += __shfl_xor(pA, 1); pB += __shfl_xor(pB, 1);
            pA += __shfl_xor(pA, 2); pB += __shfl_xor(pB, 2);
            float uA = inv_n / pA;               // IEEE div, matches ref
            float uB = inv_n / pB;
            // col sums: powers ascend as m descends; start = wc = w^(49-16s)
            float gA = wcA, gB = wcB;
            #pragma unroll
            for (int m = 15; m >= 0; m--) {
                cp[m] = fmaf(gA, uA, fmaf(gB, uB, cp[m]));
                gA *= wA; gB *= wB;
            }
            if (seg == 3) c64 += uA + uB;        // col j=64: M=1
        }
        #pragma unroll
        for (int m = 0; m < 16; m++)
            atomicAdd(&sl[h16 * KP1 + seg * 16 + m], cp[m]);
        if (seg == 3) atomicAdd(&sl[h16 * KP1 + 64], c64);
        __syncthreads();
        if (tid < KP1) {
            float cs = 0.0f;
            #pragma unroll
            for (int g = 0; g < SLABR; g++) cs += sl[g * KP1 + tid];
            float nuj = (tid == KK) ? nu_last : inv_n;
            vprev_sh[tid] = v_sh[tid];           // keep vt_{199} for final u
            v_sh[tid] = nuj / cs;
        }
        __syncthreads();
    }

    // ---- final pass A: ut per row (vs v_prev) -> stash in srt (sort buf dead) ----
    {
        float vp[16], vp64;
        #pragma unroll
        for (int j = 0; j < 16; j++) vp[j] = vprev_sh[seg * 16 + j];
        vp64 = vprev_sh[64];
        #pragma unroll
        for (int r = 0; r < ROWS_PT; r++) {
            int row = team + NTEAMS * r;
            float wv = w_[r], wcv = wc_[r];
            float h = vp[0];
            #pragma unroll
            for (int m = 1; m < 16; m++) h = fmaf(h, wv, vp[m]);
            float p = h * wcv;
            if (seg == 3) p += vp64;
            p += __shfl_xor(p, 1);
            p += __shfl_xor(p, 2);
            if (seg == 0) srt[row] = inv_n / p;
        }
    }
    __syncthreads();

    // ---- final pass B: outputs + norm (runs once) ----
    {
        float vloc[16], v64;
        #pragma unroll
        for (int j = 0; j < 16; j++) vloc[j] = v_sh[seg * 16 + j];
        v64 = v_sh[64];

        double npart = 0.0;
        #pragma unroll
        for (int r = 0; r < ROWS_PT; r++) {
            int row = team + NTEAMS * r;
            float si = ss[row];
            float u  = srt[row];
            float wv = w_[r];
            // Gamma row segment: gm[m] = ut * w^(64-16s-m) * vt[m]
            float gm[16];
            float ug = u * wc_[r];
            #pragma unroll
            for (int m = 15; m >= 0; m--) { gm[m] = ug * vloc[m]; ug *= wv; }

            float g0sum = 0.0f;
            float* orow = out + ((size_t)b * NN + row) * KK + seg * 16;
            #pragma unroll
            for (int q = 0; q < 4; q++) {
                float4 o;
                #define DO_K(kk_, fld) { const int kl = 4 * q + kk_;            \
                    float dd = fabsf(topk_sh[seg * 16 + kl] - si);              \
                    float e  = __builtin_amdgcn_exp2f(dd * lt);                 \
                    float sg = 1.0f / (1.0f + e) + 1e-20f;                      \
                    float g0 = (sg * recS_sh[seg * 16 + kl]) * inv_n;           \
                    g0sum += g0;                                                \
                    float df = gm[kl] - g0; npart += (double)df * (double)df;   \
                    o.fld = gm[kl] * 2048.0f; }
                DO_K(0, x) DO_K(1, y) DO_K(2, z) DO_K(3, w)
                #undef DO_K
                ((float4*)orow)[q] = o;
            }
            float gtot = g0sum;
            gtot += __shfl_xor(gtot, 1);
            gtot += __shfl_xor(gtot, 2);
            if (seg == 3) {
                float last = inv_n - gtot;
                last = fminf(fmaxf(last, 1e-20f), 1.0f - 1e-20f);   // clip
                float gm64 = u * v64;            // M_{i,64} = w^0 = 1
                float df = gm64 - last;
                npart += (double)df * (double)df;
            }
        }

        __syncthreads();
        red_sh[tid] = npart;
        __syncthreads();
        for (int s2 = NTHREADS / 2; s2 > 0; s2 >>= 1) {
            if (tid < s2) red_sh[tid] += red_sh[tid + s2];
            __syncthreads();
        }
        if (tid == 0) atomicAdd(norm_acc, red_sh[0]);
    }
}

// ---- kernel 3: finalize norm ----
__global__ void finalize_kernel(const double* __restrict__ norm_acc, float* __restrict__ out) {
    if (threadIdx.x == 0 && blockIdx.x == 0)
        out[(size_t)BS * NN * KK] = (float)sqrt(*norm_acc);
}

extern "C" void kernel_launch(void* const* d_in, const int* in_sizes, int n_in,
                              void* d_out, int out_size, void* d_ws, size_t ws_size,
                              hipStream_t stream) {
    const float* scores = (const float*)d_in[0];
    const float* W = (const float*)d_in[1];
    float* out = (float*)d_out;

    // ws layout: [0..3] max_enc(0), [4..7] inf_count(0),
    //            [8..15] norm_acc double(0), [16..19] min_enc(0xFFFFFFFF)
    unsigned* maxenc = (unsigned*)d_ws;
    unsigned* infc   = maxenc + 1;
    double*  nacc    = (double*)((char*)d_ws + 8);
    unsigned* minenc = (unsigned*)((char*)d_ws + 16);

    hipMemsetAsync(d_ws, 0, 16, stream);
    hipMemsetAsync((char*)d_ws + 16, 0xFF, 4, stream);

    hipLaunchKernelGGL(minmax_kernel, dim3(256), dim3(256), 0, stream,
                       scores, maxenc, minenc, infc);
    hipLaunchKernelGGL(sink_main, dim3(BS), dim3(NTHREADS), 0, stream,
                       scores, W, out, maxenc, minenc, infc, nacc);
    hipLaunchKernelGGL(finalize_kernel, dim3(1), dim3(64), 0, stream, nacc, out);
}